// Round 16
// baseline (343.855 us; speedup 1.0000x reference)
//
#include <hip/hip_runtime.h>
#include <hip/hip_cooperative_groups.h>

namespace cg = cooperative_groups;

#define N1 8192
#define N2 8192
#define KNN 32
#define R2_F32 0.009999999776482582f   // f32(0.1*0.1), bit-exact vs np ref (rounds 2..14)

#define GDIM 10
#define NCELLS (GDIM * GDIM * GDIM)
#define CELL_W 0.109375f               // 7/64: exact in f32
#define INV_W  9.142857142857142f
#define CAP 40                         // bucket capacity; P(overflow) ~ 5e-8
#define HCAP 128                       // per-query hit buffer (E[hits]~34)
#define PRUNE2 0.0105f                 // cell min-dist^2 prune (margin >> gram noise)

// ---- ws layout ----
// 0    : cnt [1000] i32 (zeroed in-kernel each call)
// 4096 : pts [1000*CAP] float4 (x,y,z,(float)j)
#define WS_CNT 0
#define WS_PTS 4096

#define NBLOCKS 1024   // x256 thr = 4 blocks/CU exactly (co-residency for cooperative)

__device__ __forceinline__ int cell_coord(float v) {
    int c = (int)(v * INV_W);
    return c > (GDIM - 1) ? (GDIM - 1) : c;
}

__device__ __forceinline__ int prefix_lt(unsigned long long m) {
    return (int)__builtin_amdgcn_mbcnt_hi(
        (unsigned)(m >> 32),
        __builtin_amdgcn_mbcnt_lo((unsigned)m, 0u));
}

__global__ __launch_bounds__(256, 4) void k_fused(
    const float* __restrict__ p1, const float* __restrict__ p2,
    int* __restrict__ cnt, float4* __restrict__ pts,
    float* __restrict__ map_f, float* __restrict__ cnt_f, float* __restrict__ out_f)
{
    cg::grid_group grid = cg::this_grid();
    const int tid = (int)(blockIdx.x * blockDim.x + threadIdx.x);

    // ---- Phase A: zero cell counters (atomic: coherent at device scope) ----
    if (tid < NCELLS) atomicExch(&cnt[tid], 0);
    __threadfence();
    grid.sync();

    // ---- Phase B: direct-bucket scatter ----
    if (tid < N2) {
        const float x = p2[3 * tid], y = p2[3 * tid + 1], z = p2[3 * tid + 2];
        const int c = (cell_coord(x) * GDIM + cell_coord(y)) * GDIM + cell_coord(z);
        const int slot = atomicAdd(&cnt[c], 1);   // intra-cell order nondet: fixed by sort
        if (slot < CAP) pts[c * CAP + slot] = make_float4(x, y, z, (float)tid);
    }
    __threadfence();   // release pts to device scope (cross-XCD, G16)
    grid.sync();
    __threadfence();   // acquire: no stale L2 lines before gathering

    // ---- Phase C: persistent query loop (round-14 body) ----
    __shared__ float4 hits[4][HCAP];    // per-wave private
    __shared__ int cum_l[4][32];
    __shared__ int adj_l[4][32];
    const int w    = (int)(threadIdx.x >> 6);
    const int lane = (int)(threadIdx.x & 63);

    for (int qg = (int)blockIdx.x; qg < N1 / 4; qg += NBLOCKS) {
        const int q = qg * 4 + w;

        const float qx = p1[3 * q], qy = p1[3 * q + 1], qz = p1[3 * q + 2];
        // bit-exact numpy-style s1 (do not change)
        const float s1 = __fadd_rn(__fadd_rn(__fmul_rn(qx, qx), __fmul_rn(qy, qy)),
                                   __fmul_rn(qz, qz));

        const int cx = cell_coord(qx), cy = cell_coord(qy), cz = cell_coord(qz);

        // Lanes 0..26 own one neighbor cell: length + min-dist^2 prune.
        int len = 0, id = 0;
        if (lane < 27) {
            const int ax = cx + lane / 9 - 1;
            const int ay = cy + (lane / 3) % 3 - 1;
            const int az = cz + lane % 3 - 1;
            const bool valid = (unsigned)ax < GDIM && (unsigned)ay < GDIM && (unsigned)az < GDIM;
            if (valid) {
                id = (ax * GDIM + ay) * GDIM + az;
                const float gx = fmaxf(0.0f, fmaxf((float)ax * CELL_W - qx, qx - (float)(ax + 1) * CELL_W));
                const float gy = fmaxf(0.0f, fmaxf((float)ay * CELL_W - qy, qy - (float)(ay + 1) * CELL_W));
                const float gz = fmaxf(0.0f, fmaxf((float)az * CELL_W - qz, qz - (float)(az + 1) * CELL_W));
                const float mind2 = gx * gx + gy * gy + gz * gz;
                if (mind2 <= PRUNE2) {
                    int c = cnt[id];
                    len = c < CAP ? c : CAP;
                }
            }
        }

        // Inclusive scan of len over lanes 0..31.
        int cum = len;
#pragma unroll
        for (int d = 1; d < 32; d <<= 1) {
            const int v = __shfl_up(cum, d, 64);
            if (lane >= d) cum += v;
        }
        const int T = __shfl(cum, 26, 64);
        if (lane < 32) {
            cum_l[w][lane] = cum;
            adj_l[w][lane] = id * CAP - (cum - len);   // pts_idx = g + adj[run]
        }

        // Dense gather over the virtual concatenation of kept runs.
        int hcnt = 0;
        for (int g0 = 0; g0 < T; g0 += 64) {
            const int g = g0 + lane;
            const bool active = g < T;
            int lo = 0;
#pragma unroll
            for (int st = 16; st > 0; st >>= 1)
                if (cum_l[w][lo + st - 1] <= g) lo += st;
            float4 e = make_float4(2.0f, 2.0f, 2.0f, 0.0f);   // dummy: far away
            if (active) e = pts[g + adj_l[w][lo]];
            // bit-exact f32 gram classification (do not change)
            const float s2  = __fadd_rn(__fadd_rn(__fmul_rn(e.x, e.x), __fmul_rn(e.y, e.y)),
                                        __fmul_rn(e.z, e.z));
            const float dot = __fmaf_rn(qz, e.z, __fmaf_rn(qy, e.y, __fmul_rn(qx, e.x)));
            const float d2  = __fsub_rn(__fadd_rn(s1, s2), __fadd_rn(dot, dot));
            const bool within = active && (d2 <= R2_F32);
            const unsigned long long m = __ballot(within);
            if (m) {
                const int pos = hcnt + prefix_lt(m);
                if (within && pos < HCAP) hits[w][pos] = e;
                hcnt += (int)__popcll(m);
            }
        }

        // Restore index order: key = (j<<7)|bufpos, 128-element bitonic sort.
        const int cap2 = hcnt < HCAP ? hcnt : HCAP;
        int k0 = 0x7FFFFFFF, k1 = 0x7FFFFFFF;
        if (lane < cap2)      k0 = (((int)hits[w][lane].w) << 7) | lane;
        if (lane + 64 < cap2) k1 = (((int)hits[w][lane + 64].w) << 7) | (lane + 64);
        for (int k = 2; k <= 128; k <<= 1) {
            for (int s = k >> 1; s > 0; s >>= 1) {
                if (s == 64) {
                    const int lo2 = k0 < k1 ? k0 : k1;
                    const int hi2 = k0 < k1 ? k1 : k0;
                    k0 = lo2; k1 = hi2;
                } else {
                    const int p0 = __shfl_xor(k0, s, 64);
                    const int p1 = __shfl_xor(k1, s, 64);
                    const bool lower = (lane & s) == 0;
                    const bool asc0  = ((lane     ) & k) == 0;
                    const bool asc1  = ((lane + 64) & k) == 0;
                    k0 = (lower == asc0) ? (k0 < p0 ? k0 : p0) : (k0 > p0 ? k0 : p0);
                    k1 = (lower == asc1) ? (k1 < p1 ? k1 : p1) : (k1 > p1 ? k1 : p1);
                }
            }
        }

        const int outc = hcnt < KNN ? hcnt : KNN;
        if (lane < KNN) {
            const int s = q * KNN + lane;
            float* o = out_f + s * 3;
            if (lane < outc) {
                const float4 e = hits[w][k0 & 127];
                map_f[s] = (float)(k0 >> 7);
                o[0] = e.x; o[1] = e.y; o[2] = e.z;
            } else {
                map_f[s] = 0.0f;
                o[0] = 0.0f; o[1] = 0.0f; o[2] = 0.0f;
            }
        }
        if (lane == 0) cnt_f[q] = (float)outc;
    }
}

extern "C" void kernel_launch(void* const* d_in, const int* in_sizes, int n_in,
                              void* d_out, int out_size, void* d_ws, size_t ws_size,
                              hipStream_t stream) {
    const float* p1 = (const float*)d_in[0];
    const float* p2 = (const float*)d_in[1];
    float* out = (float*)d_out;

    float* map_f = out;                        // N1*KNN
    float* cnt_f = out + (size_t)N1 * KNN;     // N1
    float* out_f = cnt_f + N1;                 // N1*KNN*3

    char* ws = (char*)d_ws;
    int*    cnt = (int*)(ws + WS_CNT);
    float4* pts = (float4*)(ws + WS_PTS);

    void* args[] = {(void*)&p1, (void*)&p2, (void*)&cnt, (void*)&pts,
                    (void*)&map_f, (void*)&cnt_f, (void*)&out_f};
    hipLaunchCooperativeKernel((const void*)k_fused, dim3(NBLOCKS), dim3(256),
                               args, 0, stream);
}

// Round 17
// 21.787 us; speedup vs baseline: 15.7828x; 15.7828x over previous
//
#include <hip/hip_runtime.h>

#define N1 8192
#define N2 8192
#define KNN 32
#define R2_F32 0.009999999776482582f   // f32(0.1*0.1), bit-exact vs np ref (rounds 2..14)

#define GDIM 10
#define NCELLS (GDIM * GDIM * GDIM)
#define CELL_W 0.109375f               // 7/64: exact in f32
#define INV_W  9.142857142857142f
#define CAP 40                         // bucket capacity; P(cell>40) ~ 1e-9
#define HCAP 128                       // per-query hit buffer (E[hits]~34)
#define PRUNE2 0.0105f                 // cell min-dist^2 prune (margin >> gram noise)

// ---- ws layout ----
// 0    : cnt [1000] i32  (written unconditionally by k_build -- no memset)
// 4096 : pts [1000*CAP] float4 (x,y,z,(float)j), index-sorted within cell
#define WS_CNT 0
#define WS_PTS 4096

struct F3 { float x, y, z; };

__device__ __forceinline__ F3 ld3(const float* __restrict__ p, int j) {
    F3 r;
    r.x = p[3 * j + 0];
    r.y = p[3 * j + 1];
    r.z = p[3 * j + 2];
    return r;
}

__device__ __forceinline__ int cell_coord(float v) {
    int c = (int)(v * INV_W);
    return c > (GDIM - 1) ? (GDIM - 1) : c;
}

__device__ __forceinline__ int prefix_lt(unsigned long long m) {
    return (int)__builtin_amdgcn_mbcnt_hi(
        (unsigned)(m >> 32),
        __builtin_amdgcn_mbcnt_lo((unsigned)m, 0u));
}

// Atomic-free build: one block per cell; 4 waves scan 4 index-slices of p2,
// ballot-compact members (index order preserved), LDS merge -> bucket + count.
__global__ __launch_bounds__(256) void k_build(const float* __restrict__ p2,
                                               int* __restrict__ cnt,
                                               float4* __restrict__ pts) {
    __shared__ float4 buf[4][CAP];
    __shared__ int    cl[4];
    const int w    = (int)(threadIdx.x >> 6);
    const int lane = (int)(threadIdx.x & 63);
    const int c    = (int)blockIdx.x;
    const int ccx = c / 100, ccy = (c / 10) % 10, ccz = c % 10;

    int count = 0;
    const int jofs = w * (N2 / 4);

    auto proc = [&](const F3& p, int jb) {
        const bool match = (cell_coord(p.x) == ccx) &&
                           (cell_coord(p.y) == ccy) &&
                           (cell_coord(p.z) == ccz);
        const unsigned long long m = __ballot(match);
        if (m) {   // rare: ~8% of chunks for a given cell
            const int pos = count + prefix_lt(m);
            if (match && pos < CAP)
                buf[w][pos] = make_float4(p.x, p.y, p.z, (float)(jb + lane));
            count += (int)__popcll(m);
        }
    };

    // 4-deep register pipeline over this wave's 32 chunks of 64 points.
    constexpr int NMB = (N2 / 4) / 256;  // 8 macro-iterations of 4 chunks
    F3 b0 = ld3(p2, jofs + 0 * 64 + lane);
    F3 b1 = ld3(p2, jofs + 1 * 64 + lane);
    F3 b2 = ld3(p2, jofs + 2 * 64 + lane);
    F3 b3 = ld3(p2, jofs + 3 * 64 + lane);
    for (int mb = 0; mb < NMB; ++mb) {
        const int nb = (mb + 1 < NMB) ? (mb + 1) : 0;
        F3 n0 = ld3(p2, jofs + nb * 256 + 0 * 64 + lane);
        F3 n1 = ld3(p2, jofs + nb * 256 + 1 * 64 + lane);
        F3 n2 = ld3(p2, jofs + nb * 256 + 2 * 64 + lane);
        F3 n3 = ld3(p2, jofs + nb * 256 + 3 * 64 + lane);
        const int jb = jofs + mb * 256;
        proc(b0, jb + 0 * 64);
        proc(b1, jb + 1 * 64);
        proc(b2, jb + 2 * 64);
        proc(b3, jb + 3 * 64);
        b0 = n0; b1 = n1; b2 = n2; b3 = n3;
    }

    if (lane == 0) cl[w] = count;
    __syncthreads();

    const int c0 = cl[0], c1 = cl[1], c2 = cl[2], c3 = cl[3];
    int start = 0;
    if (w > 0) start += c0;
    if (w > 1) start += c1;
    if (w > 2) start += c2;
    const int st = start < CAP ? start : CAP;
    int ns = CAP - st;
    if (count < ns) ns = count;
    if (lane < ns) pts[c * CAP + st + lane] = buf[w][lane];   // slice order == index order
    if (w == 0 && lane == 0) cnt[c] = c0 + c1 + c2 + c3;
}

// Query kernel: verbatim from round 14 (passed, absmax 0).
__global__ __launch_bounds__(256) void k_query(
    const float* __restrict__ p1, const float4* __restrict__ pts,
    const int* __restrict__ cnt,
    float* __restrict__ map_f, float* __restrict__ cnt_f, float* __restrict__ out_f)
{
    __shared__ float4 hits[4][HCAP];    // per-wave private
    __shared__ int cum_l[4][32];
    __shared__ int adj_l[4][32];
    const int w    = (int)(threadIdx.x >> 6);
    const int lane = (int)(threadIdx.x & 63);
    const int q    = (int)blockIdx.x * 4 + w;

    const float qx = p1[3 * q], qy = p1[3 * q + 1], qz = p1[3 * q + 2];
    // bit-exact numpy-style s1 (do not change)
    const float s1 = __fadd_rn(__fadd_rn(__fmul_rn(qx, qx), __fmul_rn(qy, qy)),
                               __fmul_rn(qz, qz));

    const int cx = cell_coord(qx), cy = cell_coord(qy), cz = cell_coord(qz);

    // Lanes 0..26 own one neighbor cell: length + min-dist^2 prune.
    int len = 0, id = 0;
    if (lane < 27) {
        const int ax = cx + lane / 9 - 1;
        const int ay = cy + (lane / 3) % 3 - 1;
        const int az = cz + lane % 3 - 1;
        const bool valid = (unsigned)ax < GDIM && (unsigned)ay < GDIM && (unsigned)az < GDIM;
        if (valid) {
            id = (ax * GDIM + ay) * GDIM + az;
            const float gx = fmaxf(0.0f, fmaxf((float)ax * CELL_W - qx, qx - (float)(ax + 1) * CELL_W));
            const float gy = fmaxf(0.0f, fmaxf((float)ay * CELL_W - qy, qy - (float)(ay + 1) * CELL_W));
            const float gz = fmaxf(0.0f, fmaxf((float)az * CELL_W - qz, qz - (float)(az + 1) * CELL_W));
            const float mind2 = gx * gx + gy * gy + gz * gz;
            if (mind2 <= PRUNE2) {
                int c = cnt[id];
                len = c < CAP ? c : CAP;
            }
        }
    }

    // Inclusive scan of len over lanes 0..31.
    int cum = len;
#pragma unroll
    for (int d = 1; d < 32; d <<= 1) {
        const int v = __shfl_up(cum, d, 64);
        if (lane >= d) cum += v;
    }
    const int T = __shfl(cum, 26, 64);
    if (lane < 32) {
        cum_l[w][lane] = cum;
        adj_l[w][lane] = id * CAP - (cum - len);   // pts_idx = g + adj[run]
    }

    // Dense gather over the virtual concatenation of kept runs.
    int hcnt = 0;
    for (int g0 = 0; g0 < T; g0 += 64) {
        const int g = g0 + lane;
        const bool active = g < T;
        int lo = 0;
#pragma unroll
        for (int st = 16; st > 0; st >>= 1)
            if (cum_l[w][lo + st - 1] <= g) lo += st;
        float4 e = make_float4(2.0f, 2.0f, 2.0f, 0.0f);   // dummy: far away
        if (active) e = pts[g + adj_l[w][lo]];
        // bit-exact f32 gram classification (do not change)
        const float s2  = __fadd_rn(__fadd_rn(__fmul_rn(e.x, e.x), __fmul_rn(e.y, e.y)),
                                    __fmul_rn(e.z, e.z));
        const float dot = __fmaf_rn(qz, e.z, __fmaf_rn(qy, e.y, __fmul_rn(qx, e.x)));
        const float d2  = __fsub_rn(__fadd_rn(s1, s2), __fadd_rn(dot, dot));
        const bool within = active && (d2 <= R2_F32);
        const unsigned long long m = __ballot(within);
        if (m) {
            const int pos = hcnt + prefix_lt(m);
            if (within && pos < HCAP) hits[w][pos] = e;
            hcnt += (int)__popcll(m);
        }
    }

    // Restore index order: key = (j<<7)|bufpos, 128-element bitonic sort.
    const int cap2 = hcnt < HCAP ? hcnt : HCAP;
    int k0 = 0x7FFFFFFF, k1 = 0x7FFFFFFF;
    if (lane < cap2)      k0 = (((int)hits[w][lane].w) << 7) | lane;
    if (lane + 64 < cap2) k1 = (((int)hits[w][lane + 64].w) << 7) | (lane + 64);
    for (int k = 2; k <= 128; k <<= 1) {
        for (int s = k >> 1; s > 0; s >>= 1) {
            if (s == 64) {
                const int lo2 = k0 < k1 ? k0 : k1;
                const int hi2 = k0 < k1 ? k1 : k0;
                k0 = lo2; k1 = hi2;
            } else {
                const int p0 = __shfl_xor(k0, s, 64);
                const int p1 = __shfl_xor(k1, s, 64);
                const bool lower = (lane & s) == 0;
                const bool asc0  = ((lane     ) & k) == 0;
                const bool asc1  = ((lane + 64) & k) == 0;
                k0 = (lower == asc0) ? (k0 < p0 ? k0 : p0) : (k0 > p0 ? k0 : p0);
                k1 = (lower == asc1) ? (k1 < p1 ? k1 : p1) : (k1 > p1 ? k1 : p1);
            }
        }
    }

    const int outc = hcnt < KNN ? hcnt : KNN;
    if (lane < KNN) {
        const int s = q * KNN + lane;
        float* o = out_f + s * 3;
        if (lane < outc) {
            const float4 e = hits[w][k0 & 127];
            map_f[s] = (float)(k0 >> 7);
            o[0] = e.x; o[1] = e.y; o[2] = e.z;
        } else {
            map_f[s] = 0.0f;
            o[0] = 0.0f; o[1] = 0.0f; o[2] = 0.0f;
        }
    }
    if (lane == 0) cnt_f[q] = (float)outc;
}

extern "C" void kernel_launch(void* const* d_in, const int* in_sizes, int n_in,
                              void* d_out, int out_size, void* d_ws, size_t ws_size,
                              hipStream_t stream) {
    const float* p1 = (const float*)d_in[0];
    const float* p2 = (const float*)d_in[1];
    float* out = (float*)d_out;

    float* map_f = out;                        // N1*KNN
    float* cnt_f = out + (size_t)N1 * KNN;     // N1
    float* out_f = cnt_f + N1;                 // N1*KNN*3

    char* ws = (char*)d_ws;
    int*    cnt = (int*)(ws + WS_CNT);
    float4* pts = (float4*)(ws + WS_PTS);

    hipLaunchKernelGGL(k_build, dim3(NCELLS), dim3(256), 0, stream, p2, cnt, pts);
    hipLaunchKernelGGL(k_query, dim3(N1 / 4), dim3(256), 0, stream,
                       p1, pts, cnt, map_f, cnt_f, out_f);
}

// Round 18
// 21.234 us; speedup vs baseline: 16.1934x; 1.0260x over previous
//
#include <hip/hip_runtime.h>

#define N1 8192
#define N2 8192
#define KNN 32
#define R2_F32 0.009999999776482582f   // f32(0.1*0.1), bit-exact vs np ref (rounds 2..17)

#define GDIM 10
#define NCELLS (GDIM * GDIM * GDIM)
#define CELL_W 0.109375f               // 7/64: exact in f32
#define INV_W  9.142857142857142f
#define CAP 40                         // bucket capacity; P(cell>40) ~ 1e-9
#define HCAP 128                       // per-query hit buffer (E[hits]~34)
#define PRUNE2 0.0105f                 // cell min-dist^2 prune (margin >> gram noise)

// ---- ws layout ----
// 0    : cnt [1000] i32  (written unconditionally by k_build -- no memset)
// 4096 : pts [1000*CAP] float4 (x,y,z,(float)j), index-sorted within cell
#define WS_CNT 0
#define WS_PTS 4096

struct F3 { float x, y, z; };

__device__ __forceinline__ F3 ld3(const float* __restrict__ p, int j) {
    F3 r;
    r.x = p[3 * j + 0];
    r.y = p[3 * j + 1];
    r.z = p[3 * j + 2];
    return r;
}

__device__ __forceinline__ int cell_coord(float v) {
    int c = (int)(v * INV_W);
    return c > (GDIM - 1) ? (GDIM - 1) : c;
}

__device__ __forceinline__ int prefix_lt(unsigned long long m) {
    return (int)__builtin_amdgcn_mbcnt_hi(
        (unsigned)(m >> 32),
        __builtin_amdgcn_mbcnt_lo((unsigned)m, 0u));
}

// Atomic-free build (verbatim from round 17, passed): one block per cell; 4 waves
// scan 4 index-slices of p2, ballot-compact members, LDS merge -> bucket + count.
__global__ __launch_bounds__(256) void k_build(const float* __restrict__ p2,
                                               int* __restrict__ cnt,
                                               float4* __restrict__ pts) {
    __shared__ float4 buf[4][CAP];
    __shared__ int    cl[4];
    const int w    = (int)(threadIdx.x >> 6);
    const int lane = (int)(threadIdx.x & 63);
    const int c    = (int)blockIdx.x;
    const int ccx = c / 100, ccy = (c / 10) % 10, ccz = c % 10;

    int count = 0;
    const int jofs = w * (N2 / 4);

    auto proc = [&](const F3& p, int jb) {
        const bool match = (cell_coord(p.x) == ccx) &&
                           (cell_coord(p.y) == ccy) &&
                           (cell_coord(p.z) == ccz);
        const unsigned long long m = __ballot(match);
        if (m) {
            const int pos = count + prefix_lt(m);
            if (match && pos < CAP)
                buf[w][pos] = make_float4(p.x, p.y, p.z, (float)(jb + lane));
            count += (int)__popcll(m);
        }
    };

    constexpr int NMB = (N2 / 4) / 256;
    F3 b0 = ld3(p2, jofs + 0 * 64 + lane);
    F3 b1 = ld3(p2, jofs + 1 * 64 + lane);
    F3 b2 = ld3(p2, jofs + 2 * 64 + lane);
    F3 b3 = ld3(p2, jofs + 3 * 64 + lane);
    for (int mb = 0; mb < NMB; ++mb) {
        const int nb = (mb + 1 < NMB) ? (mb + 1) : 0;
        F3 n0 = ld3(p2, jofs + nb * 256 + 0 * 64 + lane);
        F3 n1 = ld3(p2, jofs + nb * 256 + 1 * 64 + lane);
        F3 n2 = ld3(p2, jofs + nb * 256 + 2 * 64 + lane);
        F3 n3 = ld3(p2, jofs + nb * 256 + 3 * 64 + lane);
        const int jb = jofs + mb * 256;
        proc(b0, jb + 0 * 64);
        proc(b1, jb + 1 * 64);
        proc(b2, jb + 2 * 64);
        proc(b3, jb + 3 * 64);
        b0 = n0; b1 = n1; b2 = n2; b3 = n3;
    }

    if (lane == 0) cl[w] = count;
    __syncthreads();

    const int c0 = cl[0], c1 = cl[1], c2 = cl[2], c3 = cl[3];
    int start = 0;
    if (w > 0) start += c0;
    if (w > 1) start += c1;
    if (w > 2) start += c2;
    const int st = start < CAP ? start : CAP;
    int ns = CAP - st;
    if (count < ns) ns = count;
    if (lane < ns) pts[c * CAP + st + lane] = buf[w][lane];
    if (w == 0 && lane == 0) cnt[c] = c0 + c1 + c2 + c3;
}

__global__ __launch_bounds__(256) void k_query(
    const float* __restrict__ p1, const float4* __restrict__ pts,
    const int* __restrict__ cnt,
    float* __restrict__ map_f, float* __restrict__ cnt_f, float* __restrict__ out_f)
{
    __shared__ float4 hits[4][HCAP];    // 8 KB, per-wave private
    const int w    = (int)(threadIdx.x >> 6);
    const int lane = (int)(threadIdx.x & 63);
    const int q    = (int)blockIdx.x * 4 + w;

    const float qx = p1[3 * q], qy = p1[3 * q + 1], qz = p1[3 * q + 2];
    // bit-exact numpy-style s1 (do not change)
    const float s1 = __fadd_rn(__fadd_rn(__fmul_rn(qx, qx), __fmul_rn(qy, qy)),
                               __fmul_rn(qz, qz));

    const int cx = cell_coord(qx), cy = cell_coord(qy), cz = cell_coord(qz);

    // Lanes 0..26 own one neighbor cell: length + min-dist^2 prune.
    int len = 0, id = 0;
    if (lane < 27) {
        const int ax = cx + lane / 9 - 1;
        const int ay = cy + (lane / 3) % 3 - 1;
        const int az = cz + lane % 3 - 1;
        const bool valid = (unsigned)ax < GDIM && (unsigned)ay < GDIM && (unsigned)az < GDIM;
        if (valid) {
            id = (ax * GDIM + ay) * GDIM + az;
            const float gx = fmaxf(0.0f, fmaxf((float)ax * CELL_W - qx, qx - (float)(ax + 1) * CELL_W));
            const float gy = fmaxf(0.0f, fmaxf((float)ay * CELL_W - qy, qy - (float)(ay + 1) * CELL_W));
            const float gz = fmaxf(0.0f, fmaxf((float)az * CELL_W - qz, qz - (float)(az + 1) * CELL_W));
            const float mind2 = gx * gx + gy * gy + gz * gz;
            if (mind2 <= PRUNE2) {
                int c = cnt[id];
                len = c < CAP ? c : CAP;
            }
        }
    }

    // Inclusive scan of len over lanes (lanes >= 27 carry T).
    int cum = len;
#pragma unroll
    for (int d = 1; d < 32; d <<= 1) {
        const int v = __shfl_up(cum, d, 64);
        if (lane >= d) cum += v;
    }
    const int T = __shfl(cum, 26, 64);
    const int adj = id * CAP - (cum - len);   // pts_idx = g + adj[run]; lives in lane r's reg

    // Dense gather over the virtual concatenation of kept runs.
    // Run lookup: 5-step binary search via register shfl (ds_bpermute), not LDS.
    int hcnt = 0;
    for (int g0 = 0; g0 < T; g0 += 64) {
        const int g = g0 + lane;
        const bool active = g < T;
        int lo = 0;
#pragma unroll
        for (int st = 16; st > 0; st >>= 1) {
            const int v = __shfl(cum, lo + st - 1, 64);
            if (v <= g) lo += st;
        }
        const int aj = __shfl(adj, lo, 64);
        float4 e = make_float4(2.0f, 2.0f, 2.0f, 0.0f);   // dummy: far away
        if (active) e = pts[g + aj];
        // bit-exact f32 gram classification (do not change)
        const float s2  = __fadd_rn(__fadd_rn(__fmul_rn(e.x, e.x), __fmul_rn(e.y, e.y)),
                                    __fmul_rn(e.z, e.z));
        const float dot = __fmaf_rn(qz, e.z, __fmaf_rn(qy, e.y, __fmul_rn(qx, e.x)));
        const float d2  = __fsub_rn(__fadd_rn(s1, s2), __fadd_rn(dot, dot));
        const bool within = active && (d2 <= R2_F32);
        const unsigned long long m = __ballot(within);
        if (m) {
            const int pos = hcnt + prefix_lt(m);
            if (within && pos < HCAP) hits[w][pos] = e;
            hcnt += (int)__popcll(m);
        }
    }

    // Rank-by-counting (replaces bitonic sort): output slot of a hit = number of
    // hits with smaller original index j (j's distinct). Broadcast LDS reads, no
    // shuffle chain. Lane owns hits[lane] and hits[lane+64].
    const int cap2 = hcnt < HCAP ? hcnt : HCAP;
    float4 e0, e1;
    int j0 = 0x7FFFFFFF, j1 = 0x7FFFFFFF;
    if (lane < cap2)      { e0 = hits[w][lane];      j0 = (int)e0.w; }
    if (lane + 64 < cap2) { e1 = hits[w][lane + 64]; j1 = (int)e1.w; }
    int r0 = 0, r1 = 0;
#pragma unroll 4
    for (int i = 0; i < cap2; ++i) {
        const int ji = (int)hits[w][i].w;   // wave-uniform address -> broadcast
        r0 += (ji < j0) ? 1 : 0;
        r1 += (ji < j1) ? 1 : 0;
    }

    const int outc = hcnt < KNN ? hcnt : KNN;
    if (lane < cap2 && r0 < KNN) {
        const int s = q * KNN + r0;
        map_f[s] = e0.w;
        float* o = out_f + s * 3;
        o[0] = e0.x; o[1] = e0.y; o[2] = e0.z;
    }
    if (lane + 64 < cap2 && r1 < KNN) {
        const int s = q * KNN + r1;
        map_f[s] = e1.w;
        float* o = out_f + s * 3;
        o[0] = e1.x; o[1] = e1.y; o[2] = e1.z;
    }
    // Zero-fill padded tail (d_out is poisoned; every element must be written).
    if (lane < KNN && lane >= outc) {
        const int s = q * KNN + lane;
        map_f[s] = 0.0f;
        float* o = out_f + s * 3;
        o[0] = 0.0f; o[1] = 0.0f; o[2] = 0.0f;
    }
    if (lane == 0) cnt_f[q] = (float)outc;
}

extern "C" void kernel_launch(void* const* d_in, const int* in_sizes, int n_in,
                              void* d_out, int out_size, void* d_ws, size_t ws_size,
                              hipStream_t stream) {
    const float* p1 = (const float*)d_in[0];
    const float* p2 = (const float*)d_in[1];
    float* out = (float*)d_out;

    float* map_f = out;                        // N1*KNN
    float* cnt_f = out + (size_t)N1 * KNN;     // N1
    float* out_f = cnt_f + N1;                 // N1*KNN*3

    char* ws = (char*)d_ws;
    int*    cnt = (int*)(ws + WS_CNT);
    float4* pts = (float4*)(ws + WS_PTS);

    hipLaunchKernelGGL(k_build, dim3(NCELLS), dim3(256), 0, stream, p2, cnt, pts);
    hipLaunchKernelGGL(k_query, dim3(N1 / 4), dim3(256), 0, stream,
                       p1, pts, cnt, map_f, cnt_f, out_f);
}

// Round 19
// 19.426 us; speedup vs baseline: 17.7008x; 1.0931x over previous
//
#include <hip/hip_runtime.h>

#define N1 8192
#define N2 8192
#define KNN 32
#define R2_F32 0.009999999776482582f   // f32(0.1*0.1), bit-exact vs np ref (rounds 2..18)

#define GDIM 10
#define NCELLS (GDIM * GDIM * GDIM)
#define CELL_W 0.109375f               // 7/64: exact in f32
#define INV_W  9.142857142857142f
#define CAP 40                         // bucket capacity; P(cell>40) ~ 1e-9
#define HCAP 128                       // per-query hit buffer (E[hits]~34)
#define PRUNE2 0.0105f                 // cell min-dist^2 prune (margin >> gram noise)

// ---- ws layout ----
// 0    : cnt [1000] i32  (written unconditionally by k_build -- no memset)
// 4096 : pts [1000*CAP] float4 (x,y,z,(float)j), index-sorted within cell
#define WS_CNT 0
#define WS_PTS 4096

#define BW  8                  // waves per build block (512 threads)
#define BSL (N2 / BW)          // 1024 points per wave slice
#define CPB 4                  // cells per build block -> 250 blocks

struct F3 { float x, y, z; };

__device__ __forceinline__ F3 ld3(const float* __restrict__ p, int j) {
    F3 r;
    r.x = p[3 * j + 0];
    r.y = p[3 * j + 1];
    r.z = p[3 * j + 2];
    return r;
}

__device__ __forceinline__ int cell_coord(float v) {
    int c = (int)(v * INV_W);
    return c > (GDIM - 1) ? (GDIM - 1) : c;
}

__device__ __forceinline__ int prefix_lt(unsigned long long m) {
    return (int)__builtin_amdgcn_mbcnt_hi(
        (unsigned)(m >> 32),
        __builtin_amdgcn_mbcnt_lo((unsigned)m, 0u));
}

// Atomic-free build, 4 cells per block: cell-id computed ONCE per point and
// matched against 4 targets (amortizes the p2 scan 4x vs round 17/18).
// 8 waves scan 8 index-slices; ballot-compact per target; LDS merge.
__global__ __launch_bounds__(512) void k_build(const float* __restrict__ p2,
                                               int* __restrict__ cnt,
                                               float4* __restrict__ pts) {
    __shared__ float4 buf[BW][CPB][CAP];   // 20 KB
    __shared__ int    cl[BW][CPB];
    const int w    = (int)(threadIdx.x >> 6);   // 0..7
    const int lane = (int)(threadIdx.x & 63);
    const int base = (int)blockIdx.x * CPB;     // cells [base, base+4)

    int count[CPB] = {0, 0, 0, 0};
    const int jofs = w * BSL;

    auto proc = [&](const F3& p, int jb) {
        const int cid = (cell_coord(p.x) * GDIM + cell_coord(p.y)) * GDIM + cell_coord(p.z);
        const unsigned dt = (unsigned)(cid - base);
#pragma unroll
        for (int t = 0; t < CPB; ++t) {
            const bool match = (dt == (unsigned)t);
            const unsigned long long m = __ballot(match);
            if (m) {   // ~rare per target
                const int pos = count[t] + prefix_lt(m);
                if (match && pos < CAP)
                    buf[w][t][pos] = make_float4(p.x, p.y, p.z, (float)(jb + lane));
                count[t] += (int)__popcll(m);
            }
        }
    };

    // 4-deep register pipeline over this wave's 16 chunks of 64 points.
    constexpr int NMB = BSL / 256;   // 4 macro-iterations
    F3 b0 = ld3(p2, jofs + 0 * 64 + lane);
    F3 b1 = ld3(p2, jofs + 1 * 64 + lane);
    F3 b2 = ld3(p2, jofs + 2 * 64 + lane);
    F3 b3 = ld3(p2, jofs + 3 * 64 + lane);
    for (int mb = 0; mb < NMB; ++mb) {
        const int nb = (mb + 1 < NMB) ? (mb + 1) : 0;
        F3 n0 = ld3(p2, jofs + nb * 256 + 0 * 64 + lane);
        F3 n1 = ld3(p2, jofs + nb * 256 + 1 * 64 + lane);
        F3 n2 = ld3(p2, jofs + nb * 256 + 2 * 64 + lane);
        F3 n3 = ld3(p2, jofs + nb * 256 + 3 * 64 + lane);
        const int jb = jofs + mb * 256;
        proc(b0, jb + 0 * 64);
        proc(b1, jb + 1 * 64);
        proc(b2, jb + 2 * 64);
        proc(b3, jb + 3 * 64);
        b0 = n0; b1 = n1; b2 = n2; b3 = n3;
    }

    if (lane == 0) {   // counts are wave-uniform
        cl[w][0] = count[0];
        cl[w][1] = count[1];
        cl[w][2] = count[2];
        cl[w][3] = count[3];
    }
    __syncthreads();

    // Merge per target cell: wave-order prefix = index order (slices ascend).
#pragma unroll
    for (int t = 0; t < CPB; ++t) {
        int startv = 0, tot = 0;
#pragma unroll
        for (int u = 0; u < BW; ++u) {
            const int cu = cl[u][t];
            if (u < w) startv += cu;
            tot += cu;
        }
        const int st = startv < CAP ? startv : CAP;
        int ns = CAP - st;
        if (count[t] < ns) ns = count[t];
        if (lane < ns) pts[(base + t) * CAP + st + lane] = buf[w][t][lane];
        if (w == 0 && lane == 0) cnt[base + t] = tot;
    }
}

// Query kernel: verbatim from round 18 (passed, absmax 0).
__global__ __launch_bounds__(256) void k_query(
    const float* __restrict__ p1, const float4* __restrict__ pts,
    const int* __restrict__ cnt,
    float* __restrict__ map_f, float* __restrict__ cnt_f, float* __restrict__ out_f)
{
    __shared__ float4 hits[4][HCAP];    // 8 KB, per-wave private
    const int w    = (int)(threadIdx.x >> 6);
    const int lane = (int)(threadIdx.x & 63);
    const int q    = (int)blockIdx.x * 4 + w;

    const float qx = p1[3 * q], qy = p1[3 * q + 1], qz = p1[3 * q + 2];
    // bit-exact numpy-style s1 (do not change)
    const float s1 = __fadd_rn(__fadd_rn(__fmul_rn(qx, qx), __fmul_rn(qy, qy)),
                               __fmul_rn(qz, qz));

    const int cx = cell_coord(qx), cy = cell_coord(qy), cz = cell_coord(qz);

    // Lanes 0..26 own one neighbor cell: length + min-dist^2 prune.
    int len = 0, id = 0;
    if (lane < 27) {
        const int ax = cx + lane / 9 - 1;
        const int ay = cy + (lane / 3) % 3 - 1;
        const int az = cz + lane % 3 - 1;
        const bool valid = (unsigned)ax < GDIM && (unsigned)ay < GDIM && (unsigned)az < GDIM;
        if (valid) {
            id = (ax * GDIM + ay) * GDIM + az;
            const float gx = fmaxf(0.0f, fmaxf((float)ax * CELL_W - qx, qx - (float)(ax + 1) * CELL_W));
            const float gy = fmaxf(0.0f, fmaxf((float)ay * CELL_W - qy, qy - (float)(ay + 1) * CELL_W));
            const float gz = fmaxf(0.0f, fmaxf((float)az * CELL_W - qz, qz - (float)(az + 1) * CELL_W));
            const float mind2 = gx * gx + gy * gy + gz * gz;
            if (mind2 <= PRUNE2) {
                int c = cnt[id];
                len = c < CAP ? c : CAP;
            }
        }
    }

    // Inclusive scan of len over lanes (lanes >= 27 carry T).
    int cum = len;
#pragma unroll
    for (int d = 1; d < 32; d <<= 1) {
        const int v = __shfl_up(cum, d, 64);
        if (lane >= d) cum += v;
    }
    const int T = __shfl(cum, 26, 64);
    const int adj = id * CAP - (cum - len);   // pts_idx = g + adj[run]

    // Dense gather over the virtual concatenation of kept runs.
    int hcnt = 0;
    for (int g0 = 0; g0 < T; g0 += 64) {
        const int g = g0 + lane;
        const bool active = g < T;
        int lo = 0;
#pragma unroll
        for (int st = 16; st > 0; st >>= 1) {
            const int v = __shfl(cum, lo + st - 1, 64);
            if (v <= g) lo += st;
        }
        const int aj = __shfl(adj, lo, 64);
        float4 e = make_float4(2.0f, 2.0f, 2.0f, 0.0f);   // dummy: far away
        if (active) e = pts[g + aj];
        // bit-exact f32 gram classification (do not change)
        const float s2  = __fadd_rn(__fadd_rn(__fmul_rn(e.x, e.x), __fmul_rn(e.y, e.y)),
                                    __fmul_rn(e.z, e.z));
        const float dot = __fmaf_rn(qz, e.z, __fmaf_rn(qy, e.y, __fmul_rn(qx, e.x)));
        const float d2  = __fsub_rn(__fadd_rn(s1, s2), __fadd_rn(dot, dot));
        const bool within = active && (d2 <= R2_F32);
        const unsigned long long m = __ballot(within);
        if (m) {
            const int pos = hcnt + prefix_lt(m);
            if (within && pos < HCAP) hits[w][pos] = e;
            hcnt += (int)__popcll(m);
        }
    }

    // Rank-by-counting: output slot = #hits with smaller original index.
    const int cap2 = hcnt < HCAP ? hcnt : HCAP;
    float4 e0, e1;
    int j0 = 0x7FFFFFFF, j1 = 0x7FFFFFFF;
    if (lane < cap2)      { e0 = hits[w][lane];      j0 = (int)e0.w; }
    if (lane + 64 < cap2) { e1 = hits[w][lane + 64]; j1 = (int)e1.w; }
    int r0 = 0, r1 = 0;
#pragma unroll 4
    for (int i = 0; i < cap2; ++i) {
        const int ji = (int)hits[w][i].w;   // wave-uniform address -> broadcast
        r0 += (ji < j0) ? 1 : 0;
        r1 += (ji < j1) ? 1 : 0;
    }

    const int outc = hcnt < KNN ? hcnt : KNN;
    if (lane < cap2 && r0 < KNN) {
        const int s = q * KNN + r0;
        map_f[s] = e0.w;
        float* o = out_f + s * 3;
        o[0] = e0.x; o[1] = e0.y; o[2] = e0.z;
    }
    if (lane + 64 < cap2 && r1 < KNN) {
        const int s = q * KNN + r1;
        map_f[s] = e1.w;
        float* o = out_f + s * 3;
        o[0] = e1.x; o[1] = e1.y; o[2] = e1.z;
    }
    // Zero-fill padded tail (d_out is poisoned; every element must be written).
    if (lane < KNN && lane >= outc) {
        const int s = q * KNN + lane;
        map_f[s] = 0.0f;
        float* o = out_f + s * 3;
        o[0] = 0.0f; o[1] = 0.0f; o[2] = 0.0f;
    }
    if (lane == 0) cnt_f[q] = (float)outc;
}

extern "C" void kernel_launch(void* const* d_in, const int* in_sizes, int n_in,
                              void* d_out, int out_size, void* d_ws, size_t ws_size,
                              hipStream_t stream) {
    const float* p1 = (const float*)d_in[0];
    const float* p2 = (const float*)d_in[1];
    float* out = (float*)d_out;

    float* map_f = out;                        // N1*KNN
    float* cnt_f = out + (size_t)N1 * KNN;     // N1
    float* out_f = cnt_f + N1;                 // N1*KNN*3

    char* ws = (char*)d_ws;
    int*    cnt = (int*)(ws + WS_CNT);
    float4* pts = (float4*)(ws + WS_PTS);

    hipLaunchKernelGGL(k_build, dim3(NCELLS / CPB), dim3(512), 0, stream, p2, cnt, pts);
    hipLaunchKernelGGL(k_query, dim3(N1 / 4),       dim3(256), 0, stream,
                       p1, pts, cnt, map_f, cnt_f, out_f);
}